// Round 8
// baseline (305.466 us; speedup 1.0000x reference)
//
#include <hip/hip_runtime.h>
#include <math.h>

typedef unsigned short u16;
typedef unsigned int   u32;
typedef __attribute__((ext_vector_type(8))) short bf16x8;
typedef __attribute__((ext_vector_type(4))) float f32x4;

#define NNODES 40000
#define NEDGES 640000
#define NGRAPH 512
#define EFULL  (NEDGES + NNODES)
#define NB_SCAN ((NNODES + 255) / 256)

__device__ __forceinline__ float bflo(u32 u) {  // low bf16 of a u32 pair -> f32
  union { u32 i; float f; } v; v.i = u << 16; return v.f;
}
__device__ __forceinline__ float bfhi(u32 u) {  // high bf16 -> f32 (single AND)
  union { u32 i; float f; } v; v.i = u & 0xffff0000u; return v.f;
}
__device__ __forceinline__ u16 f2bf(float f) {  // RNE f32 -> bf16
  union { float f; u32 i; } v; v.f = f;
  u32 r = v.i + 0x7fffu + ((v.i >> 16) & 1u);
  return (u16)(r >> 16);
}
__device__ __forceinline__ void unpack8(uint4 u, float* f) {
  f[0] = bflo(u.x); f[1] = bfhi(u.x);
  f[2] = bflo(u.y); f[3] = bfhi(u.y);
  f[4] = bflo(u.z); f[5] = bfhi(u.z);
  f[6] = bflo(u.w); f[7] = bfhi(u.w);
}

// Wt[(layer*2+half)][n][k] = bf16(W[layer][k][n]); also zeroes deg (runs before deg_rank)
__global__ __launch_bounds__(256) void cast_w(const float* __restrict__ Wl, const float* __restrict__ Wr,
                                              u16* __restrict__ Wt, int* __restrict__ deg) {
  int i = blockIdx.x * 256 + threadIdx.x;             // 3*2*128*128 = 98304 exact
  int k = i & 127, n = (i >> 7) & 127, h = (i >> 14) & 1, L = i >> 15;
  const float* W = h ? Wr : Wl;
  Wt[i] = f2bf(W[(size_t)L * 16384 + k * 128 + n]);
  if (i < NNODES) deg[i] = 0;
}

// ---------------- CSR build (single atomic pass) ----------------

__global__ __launch_bounds__(256) void deg_rank(const int* __restrict__ ei, int* __restrict__ deg,
                                                int* __restrict__ rank) {
  int e = blockIdx.x * 256 + threadIdx.x;
  if (e >= EFULL) return;
  int d = (e < NEDGES) ? ei[NEDGES + e] : (e - NEDGES);  // dst; self loops appended
  rank[e] = atomicAdd(&deg[d], 1);                       // rank within segment (coalesced write)
}

__global__ __launch_bounds__(256) void scan_partial(const int* __restrict__ deg,
                                                    int* __restrict__ rowptr, int* __restrict__ btot) {
  __shared__ int s[256];
  int b = blockIdx.x, t = threadIdx.x, i = b * 256 + t;
  int v = (i < NNODES) ? deg[i] : 0;
  s[t] = v;
  __syncthreads();
  for (int st = 1; st < 256; st <<= 1) {
    int u = (t >= st) ? s[t - st] : 0;
    __syncthreads();
    s[t] += u;
    __syncthreads();
  }
  if (i < NNODES) rowptr[i] = s[t] - v;   // exclusive within block
  if (t == 255) btot[b] = s[255];         // raw block total
}

// adds masked block-prefix of btot; finalizes rowptr
__global__ __launch_bounds__(256) void scan_finish(int* __restrict__ rowptr, const int* __restrict__ btot) {
  __shared__ int s[256];
  int b = blockIdx.x, t = threadIdx.x;
  s[t] = (t < b && t < NB_SCAN) ? btot[t] : 0;
  __syncthreads();
  for (int st = 128; st; st >>= 1) {
    if (t < st) s[t] += s[t + st];
    __syncthreads();
  }
  int prefix = s[0];
  int i = b * 256 + t;
  if (i < NNODES) rowptr[i] += prefix;
  if (i == 0) rowptr[NNODES] = EFULL;
}

__global__ __launch_bounds__(256) void scatter_kernel(const int* __restrict__ ei,
                                                      const int* __restrict__ rowptr,
                                                      const int* __restrict__ rank,
                                                      int* __restrict__ srcs) {
  int e = blockIdx.x * 256 + threadIdx.x;
  if (e >= EFULL) return;
  int s, d;
  if (e < NEDGES) { s = ei[e]; d = ei[NEDGES + e]; } else { s = d = e - NEDGES; }
  srcs[rowptr[d] + rank[e]] = s;          // no atomics: rowptr is an L2-resident 160KB table
}

// ---------------- bf16 MFMA GEMM, swapped operands + LDS-staged coalesced stores ----------------

__global__ __launch_bounds__(256) void gemm_mfma(const u16* __restrict__ A,
                                                 const float* __restrict__ Af32,
                                                 const u16* __restrict__ Wt,
                                                 const float* __restrict__ bl, const float* __restrict__ br,
                                                 u16* __restrict__ xl, u16* __restrict__ xr) {
  __shared__ u16 Ws[128][136];
  int t = threadIdx.x;
  int half = blockIdx.y;
  const u16* Wg = Wt + (size_t)half * 16384;
#pragma unroll
  for (int it = 0; it < 8; ++it) {                    // stage 128x128 bf16 = 32 KB
    int idx = t * 8 + it * 2048;
    int n = idx >> 7, k = idx & 127;
    *(uint4*)&Ws[n][k] = *(const uint4*)&Wg[idx];
  }
  int lane = t & 63, wave = t >> 6;
  int row0 = blockIdx.x * 64 + wave * 16;
  int m = lane & 15, quad = lane >> 4;
  bf16x8 af[4];
  if (Af32) {                                         // layer 0: fused f32->bf16 A load
    const float* Ap = Af32 + (size_t)(row0 + m) * 128 + quad * 8;
#pragma unroll
    for (int s = 0; s < 4; ++s) {
      float4 u = *(const float4*)(Ap + s * 32);
      float4 v = *(const float4*)(Ap + s * 32 + 4);
      union { u16 q[8]; bf16x8 b; } pk;
      pk.q[0] = f2bf(u.x); pk.q[1] = f2bf(u.y); pk.q[2] = f2bf(u.z); pk.q[3] = f2bf(u.w);
      pk.q[4] = f2bf(v.x); pk.q[5] = f2bf(v.y); pk.q[6] = f2bf(v.z); pk.q[7] = f2bf(v.w);
      af[s] = pk.b;
    }
  } else {
    const u16* Ap = A + (size_t)(row0 + m) * 128 + quad * 8;
#pragma unroll
    for (int s = 0; s < 4; ++s) af[s] = *(const bf16x8*)(Ap + s * 32);  // B_op[k][n=row]
  }
  __syncthreads();
  const float* bias = half ? br : bl;
  u16* out = half ? xr : xl;
  f32x4 acc[8];
#pragma unroll
  for (int nt = 0; nt < 8; ++nt) acc[nt] = (f32x4){0.f, 0.f, 0.f, 0.f};
#pragma unroll
  for (int nt = 0; nt < 8; ++nt) {
    const u16* wp = &Ws[nt * 16 + m][quad * 8];       // A_op[n'=lane&15][k=quad*8+j]
#pragma unroll
    for (int s = 0; s < 4; ++s) {
      bf16x8 wf = *(const bf16x8*)(wp + s * 32);
      acc[nt] = __builtin_amdgcn_mfma_f32_16x16x32_bf16(wf, af[s], acc[nt], 0, 0, 0);
    }
  }
  __syncthreads();                                    // all waves done reading Ws
  u16 (*St)[136] = (u16(*)[136])Ws;                   // reuse as 64x136 store-staging
  int row_l = wave * 16 + m;
#pragma unroll
  for (int nt = 0; nt < 8; ++nt) {                    // D: col_D=lane&15 -> row; row_D=quad*4+r -> col
    int cb = nt * 16 + quad * 4;
    float4 b4 = *(const float4*)(bias + cb);
    u32 lo = (u32)f2bf(acc[nt][0] + b4.x) | ((u32)f2bf(acc[nt][1] + b4.y) << 16);
    u32 hi = (u32)f2bf(acc[nt][2] + b4.z) | ((u32)f2bf(acc[nt][3] + b4.w) << 16);
    uint2 pk; pk.x = lo; pk.y = hi;
    *(uint2*)&St[row_l][cb] = pk;
  }
  __syncthreads();
  int row = t >> 2, cs = (t & 3) * 32;                // 4 threads/row, 64B each: coalesced
  uint4* gp = (uint4*)(out + (size_t)(blockIdx.x * 64 + row) * 128 + cs);
#pragma unroll
  for (int k = 0; k < 4; ++k) gp[k] = *(uint4*)&St[row][cs + k * 8];
}

// ---------------- fused GATv2: 16-lane groups, depth-3 prefetched gathers ----------------

__global__ __launch_bounds__(256) void gat_node(const u16* __restrict__ xl, const u16* __restrict__ xr,
    const int* __restrict__ rowptr, const int* __restrict__ srcs,
    const float* __restrict__ att, const float* __restrict__ conv_bias,
    const float* __restrict__ gam, const float* __restrict__ bet,
    const float* __restrict__ bmn, const float* __restrict__ bvr,
    u16* __restrict__ hout) {
  int wave = threadIdx.x >> 6;
  int lane = threadIdx.x & 63;
  int node = blockIdx.x * 4 + wave;
  if (node >= NNODES) return;
  int beg = rowptr[node];
  int end = rowptr[node + 1];
  int lam = lane & 15, grp = lane >> 4;
  int cb = lam * 8;
  float xrv[8], atv[8];
  unpack8(*(const uint4*)(xr + (size_t)node * 128 + cb), xrv);
  {
    float4 a0 = *(const float4*)(att + cb);
    float4 a1 = *(const float4*)(att + cb + 4);
    atv[0] = a0.x; atv[1] = a0.y; atv[2] = a0.z; atv[3] = a0.w;
    atv[4] = a1.x; atv[5] = a1.y; atv[6] = a1.z; atv[7] = a1.w;
  }
  float acc[8] = {0.f, 0.f, 0.f, 0.f, 0.f, 0.f, 0.f, 0.f};
  float den = 0.f;

  for (int base = beg; base < end; base += 64) {
    int lim = end - base; if (lim > 64) lim = 64;
    int sreg = srcs[base + (lane < lim ? lane : 0)];
    int cnt = (lim - grp + 3) >> 2;                   // edges e = grp + 4i, e < lim
    // depth-3 prefetch pipeline: up to 12 outstanding gathers per wave
    uint4 u0, u1, u2;
    if (cnt > 0) u0 = *(const uint4*)(xl + (size_t)__shfl(sreg, grp,     64) * 128 + cb);
    if (cnt > 1) u1 = *(const uint4*)(xl + (size_t)__shfl(sreg, grp + 4, 64) * 128 + cb);
    if (cnt > 2) u2 = *(const uint4*)(xl + (size_t)__shfl(sreg, grp + 8, 64) * 128 + cb);
    for (int i = 0; i < cnt; ++i) {
      uint4 u = u0; u0 = u1; u1 = u2;
      if (i + 3 < cnt) {
        int sn = __shfl(sreg, grp + 4 * (i + 3), 64); // clamped sreg for lanes>=lim is a valid id
        u2 = *(const uint4*)(xl + (size_t)sn * 128 + cb);
      }
      float raw[8];
      unpack8(u, raw);
      float p0 = 0.f, p1 = 0.f;
#pragma unroll
      for (int q = 0; q < 8; ++q) {
        float a = raw[q] + xrv[q];
        float l = fmaxf(a, 0.2f * a);                 // leaky_relu in 2 ops
        if (q & 1) p1 = fmaf(atv[q], l, p1); else p0 = fmaf(atv[q], l, p0);
      }
      float p = p0 + p1;
      p += __shfl_xor(p, 1, 64);                      // head = 4-lane subgroup
      p += __shfl_xor(p, 2, 64);
      float w = __expf(p);                            // raw softmax: logits are O(1)
      den += w;
#pragma unroll
      for (int q = 0; q < 8; ++q) acc[q] = fmaf(w, raw[q], acc[q]);
    }
  }
#pragma unroll
  for (int q = 0; q < 8; ++q) {                       // combine the 4 groups
    acc[q] += __shfl_xor(acc[q], 16, 64);
    acc[q] += __shfl_xor(acc[q], 32, 64);
  }
  den += __shfl_xor(den, 16, 64);
  den += __shfl_xor(den, 32, 64);
  // distributed epilogue: each lane handles channels {cb+2*grp, cb+2*grp+1}
  float e0 = (grp & 2) ? ((grp & 1) ? acc[6] : acc[4]) : ((grp & 1) ? acc[2] : acc[0]);
  float e1 = (grp & 2) ? ((grp & 1) ? acc[7] : acc[5]) : ((grp & 1) ? acc[3] : acc[1]);
  int c2 = cb + 2 * grp;
  float inv = 1.f / den;
  float2 cbv = *(const float2*)(conv_bias + c2);
  float2 mnv = *(const float2*)(bmn + c2);
  float2 vrv = *(const float2*)(bvr + c2);
  float2 gmv = *(const float2*)(gam + c2);
  float2 btv = *(const float2*)(bet + c2);
  float o0 = e0 * inv + cbv.x;
  float o1 = e1 * inv + cbv.y;
  o0 = (o0 - mnv.x) * rsqrtf(vrv.x + 1e-5f) * gmv.x + btv.x;
  o1 = (o1 - mnv.y) * rsqrtf(vrv.y + 1e-5f) * gmv.y + btv.y;
  u32 pk = (u32)f2bf(fmaxf(o0, 0.f)) | ((u32)f2bf(fmaxf(o1, 0.f)) << 16);
  *(u32*)(hout + (size_t)node * 128 + c2) = pk;
}

// ---------------- fused mean pool + classifier (batch sorted -> segments) ----------------

__device__ __forceinline__ int lowb(const int* __restrict__ batch, int val) {
  int lo = 0, hi = NNODES;
  while (lo < hi) {
    int mid = (lo + hi) >> 1;
    if (batch[mid] < val) lo = mid + 1; else hi = mid;
  }
  return lo;
}

__global__ __launch_bounds__(128) void pool_classify(const u16* __restrict__ h, const int* __restrict__ batch,
    const float* __restrict__ W1, const float* __restrict__ b1,
    const float* __restrict__ W2, const float* __restrict__ b2, float* __restrict__ out) {
  __shared__ float red[2][128];
  __shared__ float pm[128];
  __shared__ float hid[64];
  int g = blockIdx.x, t = threadIdx.x;
  int lo = lowb(batch, g);
  int hi = lowb(batch, g + 1);
  int t63 = t & 63, hh = t >> 6;
  float acc0 = 0.f, acc1 = 0.f;
  for (int n = lo + hh; n < hi; n += 2) {             // 2 nodes/iter, u32 channel pairs
    u32 u = *(const u32*)(h + (size_t)n * 128 + 2 * t63);
    acc0 += bflo(u); acc1 += bfhi(u);
  }
  red[hh][2 * t63] = acc0; red[hh][2 * t63 + 1] = acc1;
  __syncthreads();
  float cnt = fmaxf((float)(hi - lo), 1.f);
  pm[t] = (red[0][t] + red[1][t]) / cnt;
  __syncthreads();
  if (t < 64) {
    float a = b1[t];
    for (int k = 0; k < 128; ++k) a += pm[k] * W1[k * 64 + t];
    hid[t] = fmaxf(a, 0.f);
  }
  __syncthreads();
  if (t < 2) {
    float o = b2[t];
    for (int k = 0; k < 64; ++k) o += hid[k] * W2[k * 2 + t];
    out[g * 2 + t] = o;
  }
}

// ---------------- launch ----------------

extern "C" void kernel_launch(void* const* d_in, const int* in_sizes, int n_in,
                              void* d_out, int out_size, void* d_ws, size_t ws_size,
                              hipStream_t stream) {
  const float* x   = (const float*)d_in[0];
  const int*   ei  = (const int*)d_in[1];
  const int*   bat = (const int*)d_in[2];
  const float* Wl  = (const float*)d_in[3];
  const float* bl  = (const float*)d_in[4];
  const float* Wr  = (const float*)d_in[5];
  const float* br  = (const float*)d_in[6];
  const float* att = (const float*)d_in[7];
  const float* cb  = (const float*)d_in[8];
  const float* gam = (const float*)d_in[9];
  const float* bet = (const float*)d_in[10];
  const float* bmn = (const float*)d_in[11];
  const float* bvr = (const float*)d_in[12];
  const float* W1  = (const float*)d_in[13];
  const float* b1  = (const float*)d_in[14];
  const float* W2  = (const float*)d_in[15];
  const float* b2  = (const float*)d_in[16];
  float* out = (float*)d_out;

  const size_t NF = (size_t)NNODES * 128;
  u16* xlb = (u16*)d_ws;
  u16* xrb = xlb + NF;
  u16* hb0 = xrb + NF;
  u16* hb1 = hb0 + NF;
  u16* Wt  = hb1 + NF;                      // 3*2*128*128 bf16
  int* btot   = (int*)(Wt + 3 * 2 * 128 * 128);
  int* deg    = btot + 256;
  int* rowptr = deg + NNODES;
  int* rank   = rowptr + NNODES + 1;
  int* srcs   = rank + EFULL;

  cast_w<<<98304 / 256, 256, 0, stream>>>(Wl, Wr, Wt, deg);

  int eb = (EFULL + 255) / 256;
  deg_rank<<<eb, 256, 0, stream>>>(ei, deg, rank);
  scan_partial<<<NB_SCAN, 256, 0, stream>>>(deg, rowptr, btot);
  scan_finish<<<NB_SCAN, 256, 0, stream>>>(rowptr, btot);
  scatter_kernel<<<eb, 256, 0, stream>>>(ei, rowptr, rank, srcs);

  const u16* hcur = hb0;                    // unused for layer 0 (f32 path)
  u16* bufs[2] = {hb0, hb1};
  for (int i = 0; i < 3; ++i) {
    u16* hnext = bufs[i & 1];
    gemm_mfma<<<dim3(NNODES / 64, 2), 256, 0, stream>>>(hcur, i == 0 ? x : nullptr,
        Wt + (size_t)i * 2 * 16384, bl + i * 128, br + i * 128, xlb, xrb);
    gat_node<<<NNODES / 4, 256, 0, stream>>>(xlb, xrb, rowptr, srcs,
        att + i * 128, cb + i * 128, gam + i * 128, bet + i * 128,
        bmn + i * 128, bvr + i * 128, hnext);
    hcur = hnext;
  }
  pool_classify<<<NGRAPH, 128, 0, stream>>>(hcur, bat, W1, b1, W2, b2, out);
}

// Round 9
// 287.043 us; speedup vs baseline: 1.0642x; 1.0642x over previous
//
#include <hip/hip_runtime.h>
#include <math.h>

typedef unsigned short u16;
typedef unsigned int   u32;
typedef __attribute__((ext_vector_type(8))) short bf16x8;
typedef __attribute__((ext_vector_type(4))) float f32x4;

#define NNODES 40000
#define NEDGES 640000
#define NGRAPH 512
#define EFULL  (NEDGES + NNODES)
#define NB_SCAN ((NNODES + 255) / 256)

__device__ __forceinline__ float bflo(u32 u) {  // low bf16 of a u32 pair -> f32
  union { u32 i; float f; } v; v.i = u << 16; return v.f;
}
__device__ __forceinline__ float bfhi(u32 u) {  // high bf16 -> f32 (single AND)
  union { u32 i; float f; } v; v.i = u & 0xffff0000u; return v.f;
}
__device__ __forceinline__ u16 f2bf(float f) {  // RNE f32 -> bf16
  union { float f; u32 i; } v; v.f = f;
  u32 r = v.i + 0x7fffu + ((v.i >> 16) & 1u);
  return (u16)(r >> 16);
}
__device__ __forceinline__ void unpack8(uint4 u, float* f) {
  f[0] = bflo(u.x); f[1] = bfhi(u.x);
  f[2] = bflo(u.y); f[3] = bfhi(u.y);
  f[4] = bflo(u.z); f[5] = bfhi(u.z);
  f[6] = bflo(u.w); f[7] = bfhi(u.w);
}

// Wt[(layer*2+half)][n][k] = bf16(W[layer][k][n]); also zeroes deg (runs before deg_rank)
__global__ __launch_bounds__(256) void cast_w(const float* __restrict__ Wl, const float* __restrict__ Wr,
                                              u16* __restrict__ Wt, int* __restrict__ deg) {
  int i = blockIdx.x * 256 + threadIdx.x;             // 3*2*128*128 = 98304 exact
  int k = i & 127, n = (i >> 7) & 127, h = (i >> 14) & 1, L = i >> 15;
  const float* W = h ? Wr : Wl;
  Wt[i] = f2bf(W[(size_t)L * 16384 + k * 128 + n]);
  if (i < NNODES) deg[i] = 0;
}

// ---------------- CSR build (single atomic pass) ----------------

__global__ __launch_bounds__(256) void deg_rank(const int* __restrict__ ei, int* __restrict__ deg,
                                                int* __restrict__ rank) {
  int e = blockIdx.x * 256 + threadIdx.x;
  if (e >= EFULL) return;
  int d = (e < NEDGES) ? ei[NEDGES + e] : (e - NEDGES);  // dst; self loops appended
  rank[e] = atomicAdd(&deg[d], 1);                       // rank within segment (coalesced write)
}

__global__ __launch_bounds__(256) void scan_partial(const int* __restrict__ deg,
                                                    int* __restrict__ rowptr, int* __restrict__ btot) {
  __shared__ int s[256];
  int b = blockIdx.x, t = threadIdx.x, i = b * 256 + t;
  int v = (i < NNODES) ? deg[i] : 0;
  s[t] = v;
  __syncthreads();
  for (int st = 1; st < 256; st <<= 1) {
    int u = (t >= st) ? s[t - st] : 0;
    __syncthreads();
    s[t] += u;
    __syncthreads();
  }
  if (i < NNODES) rowptr[i] = s[t] - v;   // exclusive within block
  if (t == 255) btot[b] = s[255];         // raw block total
}

// adds masked block-prefix of btot; finalizes rowptr
__global__ __launch_bounds__(256) void scan_finish(int* __restrict__ rowptr, const int* __restrict__ btot) {
  __shared__ int s[256];
  int b = blockIdx.x, t = threadIdx.x;
  s[t] = (t < b && t < NB_SCAN) ? btot[t] : 0;
  __syncthreads();
  for (int st = 128; st; st >>= 1) {
    if (t < st) s[t] += s[t + st];
    __syncthreads();
  }
  int prefix = s[0];
  int i = b * 256 + t;
  if (i < NNODES) rowptr[i] += prefix;
  if (i == 0) rowptr[NNODES] = EFULL;
}

__global__ __launch_bounds__(256) void scatter_kernel(const int* __restrict__ ei,
                                                      const int* __restrict__ rowptr,
                                                      const int* __restrict__ rank,
                                                      int* __restrict__ srcs) {
  int e = blockIdx.x * 256 + threadIdx.x;
  if (e >= EFULL) return;
  int s, d;
  if (e < NEDGES) { s = ei[e]; d = ei[NEDGES + e]; } else { s = d = e - NEDGES; }
  srcs[rowptr[d] + rank[e]] = s;          // no atomics: rowptr is an L2-resident 160KB table
}

// ---------------- bf16 MFMA GEMM, swapped operands + LDS-staged coalesced stores ----------------

__global__ __launch_bounds__(256) void gemm_mfma(const u16* __restrict__ A,
                                                 const float* __restrict__ Af32,
                                                 const u16* __restrict__ Wt,
                                                 const float* __restrict__ bl, const float* __restrict__ br,
                                                 u16* __restrict__ xl, u16* __restrict__ xr) {
  __shared__ u16 Ws[128][136];
  int t = threadIdx.x;
  int half = blockIdx.y;
  const u16* Wg = Wt + (size_t)half * 16384;
#pragma unroll
  for (int it = 0; it < 8; ++it) {                    // stage 128x128 bf16 = 32 KB
    int idx = t * 8 + it * 2048;
    int n = idx >> 7, k = idx & 127;
    *(uint4*)&Ws[n][k] = *(const uint4*)&Wg[idx];
  }
  int lane = t & 63, wave = t >> 6;
  int row0 = blockIdx.x * 64 + wave * 16;
  int m = lane & 15, quad = lane >> 4;
  bf16x8 af[4];
  if (Af32) {                                         // layer 0: fused f32->bf16 A load
    const float* Ap = Af32 + (size_t)(row0 + m) * 128 + quad * 8;
#pragma unroll
    for (int s = 0; s < 4; ++s) {
      float4 u = *(const float4*)(Ap + s * 32);
      float4 v = *(const float4*)(Ap + s * 32 + 4);
      union { u16 q[8]; bf16x8 b; } pk;
      pk.q[0] = f2bf(u.x); pk.q[1] = f2bf(u.y); pk.q[2] = f2bf(u.z); pk.q[3] = f2bf(u.w);
      pk.q[4] = f2bf(v.x); pk.q[5] = f2bf(v.y); pk.q[6] = f2bf(v.z); pk.q[7] = f2bf(v.w);
      af[s] = pk.b;
    }
  } else {
    const u16* Ap = A + (size_t)(row0 + m) * 128 + quad * 8;
#pragma unroll
    for (int s = 0; s < 4; ++s) af[s] = *(const bf16x8*)(Ap + s * 32);  // B_op[k][n=row]
  }
  __syncthreads();
  const float* bias = half ? br : bl;
  u16* out = half ? xr : xl;
  f32x4 acc[8];
#pragma unroll
  for (int nt = 0; nt < 8; ++nt) acc[nt] = (f32x4){0.f, 0.f, 0.f, 0.f};
#pragma unroll
  for (int nt = 0; nt < 8; ++nt) {
    const u16* wp = &Ws[nt * 16 + m][quad * 8];       // A_op[n'=lane&15][k=quad*8+j]
#pragma unroll
    for (int s = 0; s < 4; ++s) {
      bf16x8 wf = *(const bf16x8*)(wp + s * 32);
      acc[nt] = __builtin_amdgcn_mfma_f32_16x16x32_bf16(wf, af[s], acc[nt], 0, 0, 0);
    }
  }
  __syncthreads();                                    // all waves done reading Ws
  u16 (*St)[136] = (u16(*)[136])Ws;                   // reuse as 64x136 store-staging
  int row_l = wave * 16 + m;
#pragma unroll
  for (int nt = 0; nt < 8; ++nt) {                    // D: col_D=lane&15 -> row; row_D=quad*4+r -> col
    int cb = nt * 16 + quad * 4;
    float4 b4 = *(const float4*)(bias + cb);
    u32 lo = (u32)f2bf(acc[nt][0] + b4.x) | ((u32)f2bf(acc[nt][1] + b4.y) << 16);
    u32 hi = (u32)f2bf(acc[nt][2] + b4.z) | ((u32)f2bf(acc[nt][3] + b4.w) << 16);
    uint2 pk; pk.x = lo; pk.y = hi;
    *(uint2*)&St[row_l][cb] = pk;
  }
  __syncthreads();
  int row = t >> 2, cs = (t & 3) * 32;                // 4 threads/row, 64B each: coalesced
  uint4* gp = (uint4*)(out + (size_t)(blockIdx.x * 64 + row) * 128 + cs);
#pragma unroll
  for (int k = 0; k < 4; ++k) gp[k] = *(uint4*)&St[row][cs + k * 8];
}

// ---------------- fused GATv2: one node per 64-thread block ----------------
// 16-lane groups each own edges e = grp + 4i; all lanes of a group load the SAME
// srcs[] address (HW broadcast, no shuffles in the address chain). deg-Poisson
// imbalance is absorbed at wave granularity by the CU scheduler (1 wave/block).

__global__ __launch_bounds__(64) void gat_node(const u16* __restrict__ xl, const u16* __restrict__ xr,
    const int* __restrict__ rowptr, const int* __restrict__ srcs,
    const float* __restrict__ att, const float* __restrict__ conv_bias,
    const float* __restrict__ gam, const float* __restrict__ bet,
    const float* __restrict__ bmn, const float* __restrict__ bvr,
    u16* __restrict__ hout) {
  int lane = threadIdx.x;
  int node = blockIdx.x;
  int beg = rowptr[node];
  int end = rowptr[node + 1];
  int lam = lane & 15, grp = lane >> 4;
  int cb = lam * 8;
  float xrv[8], atv[8];
  unpack8(*(const uint4*)(xr + (size_t)node * 128 + cb), xrv);
  {
    float4 a0 = *(const float4*)(att + cb);
    float4 a1 = *(const float4*)(att + cb + 4);
    atv[0] = a0.x; atv[1] = a0.y; atv[2] = a0.z; atv[3] = a0.w;
    atv[4] = a1.x; atv[5] = a1.y; atv[6] = a1.z; atv[7] = a1.w;
  }
  float acc[8] = {0.f, 0.f, 0.f, 0.f, 0.f, 0.f, 0.f, 0.f};
  float den = 0.f;

  int idx = beg + grp;
  int cnt = (end - beg - grp + 3) >> 2;               // this group's edge count (deg>=1)
  int s_b = 0;
  uint4 u_nxt;
  if (cnt > 0) {
    int s_a = srcs[idx];                              // same addr across group: broadcast
    u_nxt = *(const uint4*)(xl + (size_t)s_a * 128 + cb);
    if (cnt > 1) s_b = srcs[idx + 4];
  }
  for (int i = 0; i < cnt; ++i) {
    uint4 u = u_nxt;
    if (i + 1 < cnt) {
      u_nxt = *(const uint4*)(xl + (size_t)s_b * 128 + cb);   // gather edge i+1
      if (i + 2 < cnt) s_b = srcs[idx + 4 * (i + 2)];         // src for edge i+2
    }
    float raw[8];
    unpack8(u, raw);
    float p0 = 0.f, p1 = 0.f;
#pragma unroll
    for (int q = 0; q < 8; ++q) {
      float a = raw[q] + xrv[q];
      float l = fmaxf(a, 0.2f * a);                   // leaky_relu in 2 ops
      if (q & 1) p1 = fmaf(atv[q], l, p1); else p0 = fmaf(atv[q], l, p0);
    }
    float p = p0 + p1;
    p += __shfl_xor(p, 1, 64);                        // head = 4-lane subgroup
    p += __shfl_xor(p, 2, 64);
    float w = __expf(p);                              // raw softmax: logits are O(1)
    den += w;
#pragma unroll
    for (int q = 0; q < 8; ++q) acc[q] = fmaf(w, raw[q], acc[q]);
  }
#pragma unroll
  for (int q = 0; q < 8; ++q) {                       // combine the 4 groups
    acc[q] += __shfl_xor(acc[q], 16, 64);
    acc[q] += __shfl_xor(acc[q], 32, 64);
  }
  den += __shfl_xor(den, 16, 64);
  den += __shfl_xor(den, 32, 64);
  // distributed epilogue: each lane handles channels {cb+2*grp, cb+2*grp+1}
  float e0 = (grp & 2) ? ((grp & 1) ? acc[6] : acc[4]) : ((grp & 1) ? acc[2] : acc[0]);
  float e1 = (grp & 2) ? ((grp & 1) ? acc[7] : acc[5]) : ((grp & 1) ? acc[3] : acc[1]);
  int c2 = cb + 2 * grp;
  float inv = 1.f / den;
  float2 cbv = *(const float2*)(conv_bias + c2);
  float2 mnv = *(const float2*)(bmn + c2);
  float2 vrv = *(const float2*)(bvr + c2);
  float2 gmv = *(const float2*)(gam + c2);
  float2 btv = *(const float2*)(bet + c2);
  float o0 = e0 * inv + cbv.x;
  float o1 = e1 * inv + cbv.y;
  o0 = (o0 - mnv.x) * rsqrtf(vrv.x + 1e-5f) * gmv.x + btv.x;
  o1 = (o1 - mnv.y) * rsqrtf(vrv.y + 1e-5f) * gmv.y + btv.y;
  u32 pk = (u32)f2bf(fmaxf(o0, 0.f)) | ((u32)f2bf(fmaxf(o1, 0.f)) << 16);
  *(u32*)(hout + (size_t)node * 128 + c2) = pk;
}

// ---------------- fused mean pool + classifier (batch sorted -> segments) ----------------

__device__ __forceinline__ int lowb(const int* __restrict__ batch, int val) {
  int lo = 0, hi = NNODES;
  while (lo < hi) {
    int mid = (lo + hi) >> 1;
    if (batch[mid] < val) lo = mid + 1; else hi = mid;
  }
  return lo;
}

__global__ __launch_bounds__(128) void pool_classify(const u16* __restrict__ h, const int* __restrict__ batch,
    const float* __restrict__ W1, const float* __restrict__ b1,
    const float* __restrict__ W2, const float* __restrict__ b2, float* __restrict__ out) {
  __shared__ float red[2][128];
  __shared__ float pm[128];
  __shared__ float hid[64];
  int g = blockIdx.x, t = threadIdx.x;
  int lo = lowb(batch, g);
  int hi = lowb(batch, g + 1);
  int t63 = t & 63, hh = t >> 6;
  float acc0 = 0.f, acc1 = 0.f;
  for (int n = lo + hh; n < hi; n += 2) {             // 2 nodes/iter, u32 channel pairs
    u32 u = *(const u32*)(h + (size_t)n * 128 + 2 * t63);
    acc0 += bflo(u); acc1 += bfhi(u);
  }
  red[hh][2 * t63] = acc0; red[hh][2 * t63 + 1] = acc1;
  __syncthreads();
  float cnt = fmaxf((float)(hi - lo), 1.f);
  pm[t] = (red[0][t] + red[1][t]) / cnt;
  __syncthreads();
  if (t < 64) {
    float a = b1[t];
    for (int k = 0; k < 128; ++k) a += pm[k] * W1[k * 64 + t];
    hid[t] = fmaxf(a, 0.f);
  }
  __syncthreads();
  if (t < 2) {
    float o = b2[t];
    for (int k = 0; k < 64; ++k) o += hid[k] * W2[k * 2 + t];
    out[g * 2 + t] = o;
  }
}

// ---------------- launch ----------------

extern "C" void kernel_launch(void* const* d_in, const int* in_sizes, int n_in,
                              void* d_out, int out_size, void* d_ws, size_t ws_size,
                              hipStream_t stream) {
  const float* x   = (const float*)d_in[0];
  const int*   ei  = (const int*)d_in[1];
  const int*   bat = (const int*)d_in[2];
  const float* Wl  = (const float*)d_in[3];
  const float* bl  = (const float*)d_in[4];
  const float* Wr  = (const float*)d_in[5];
  const float* br  = (const float*)d_in[6];
  const float* att = (const float*)d_in[7];
  const float* cb  = (const float*)d_in[8];
  const float* gam = (const float*)d_in[9];
  const float* bet = (const float*)d_in[10];
  const float* bmn = (const float*)d_in[11];
  const float* bvr = (const float*)d_in[12];
  const float* W1  = (const float*)d_in[13];
  const float* b1  = (const float*)d_in[14];
  const float* W2  = (const float*)d_in[15];
  const float* b2  = (const float*)d_in[16];
  float* out = (float*)d_out;

  const size_t NF = (size_t)NNODES * 128;
  u16* xlb = (u16*)d_ws;
  u16* xrb = xlb + NF;
  u16* hb0 = xrb + NF;
  u16* hb1 = hb0 + NF;
  u16* Wt  = hb1 + NF;                      // 3*2*128*128 bf16
  int* btot   = (int*)(Wt + 3 * 2 * 128 * 128);
  int* deg    = btot + 256;
  int* rowptr = deg + NNODES;
  int* rank   = rowptr + NNODES + 1;
  int* srcs   = rank + EFULL;

  cast_w<<<98304 / 256, 256, 0, stream>>>(Wl, Wr, Wt, deg);

  int eb = (EFULL + 255) / 256;
  deg_rank<<<eb, 256, 0, stream>>>(ei, deg, rank);
  scan_partial<<<NB_SCAN, 256, 0, stream>>>(deg, rowptr, btot);
  scan_finish<<<NB_SCAN, 256, 0, stream>>>(rowptr, btot);
  scatter_kernel<<<eb, 256, 0, stream>>>(ei, rowptr, rank, srcs);

  const u16* hcur = hb0;                    // unused for layer 0 (f32 path)
  u16* bufs[2] = {hb0, hb1};
  for (int i = 0; i < 3; ++i) {
    u16* hnext = bufs[i & 1];
    gemm_mfma<<<dim3(NNODES / 64, 2), 256, 0, stream>>>(hcur, i == 0 ? x : nullptr,
        Wt + (size_t)i * 2 * 16384, bl + i * 128, br + i * 128, xlb, xrb);
    gat_node<<<NNODES, 64, 0, stream>>>(xlb, xrb, rowptr, srcs,
        att + i * 128, cb + i * 128, gam + i * 128, bet + i * 128,
        bmn + i * 128, bvr + i * 128, hnext);
    hcur = hnext;
  }
  pool_classify<<<NGRAPH, 128, 0, stream>>>(hcur, bat, W1, b1, W2, b2, out);
}